// Round 1
// baseline (2920.736 us; speedup 1.0000x reference)
//
#include <hip/hip_runtime.h>
#include <hip/hip_bf16.h>

#define NN 100000
#define DIM 128

// ---------------- degree / dinv ----------------
__global__ void k_init_deg(float* __restrict__ deg, int n) {
    int i = blockIdx.x * blockDim.x + threadIdx.x;
    if (i < n) deg[i] = 1.0f;  // self-loop
}

__global__ void k_count_deg(float* __restrict__ deg, const int* __restrict__ dst, int E) {
    int e = blockIdx.x * blockDim.x + threadIdx.x;
    if (e < E) atomicAdd(&deg[dst[e]], 1.0f);
}

__global__ void k_dinv(float* __restrict__ deg, int n) {
    int i = blockIdx.x * blockDim.x + threadIdx.x;
    if (i < n) deg[i] = rsqrtf(deg[i]);  // deg >= 1 always (self-loop)
}

// ---------------- GEMM: out = (transform(in) @ W) * dinv[row], dual-store ----------------
// 16 rows/block, 256 threads. Thread computes 2 rows x 4 cols.
// RELU_IN=0: feed rows of `in` directly (layer-1 input x).
// RELU_IN=1: row-transform relu(dinv[row]*in + bin) applied at LDS staging (layer-2 input t1).
template <int RELU_IN>
__global__ void k_gemm(const float* __restrict__ in, const float* __restrict__ W,
                       const float* __restrict__ dinv, const float* __restrict__ bin,
                       float* __restrict__ out_a, float* __restrict__ out_b) {
    __shared__ float xs[16][DIM];
    const int row0 = blockIdx.x * 16;
    const int tid  = threadIdx.x;

    // stage 16x128 floats: 8 consecutive floats per thread
    {
        const int r = tid >> 4;          // 0..15
        const int c = (tid & 15) << 3;   // 0,8,...,120
        float4 v0 = *(const float4*)&in[(row0 + r) * DIM + c];
        float4 v1 = *(const float4*)&in[(row0 + r) * DIM + c + 4];
        if constexpr (RELU_IN) {
            const float dr = dinv[row0 + r];
            const float4 bb0 = *(const float4*)&bin[c];
            const float4 bb1 = *(const float4*)&bin[c + 4];
            v0.x = fmaxf(fmaf(dr, v0.x, bb0.x), 0.f);
            v0.y = fmaxf(fmaf(dr, v0.y, bb0.y), 0.f);
            v0.z = fmaxf(fmaf(dr, v0.z, bb0.z), 0.f);
            v0.w = fmaxf(fmaf(dr, v0.w, bb0.w), 0.f);
            v1.x = fmaxf(fmaf(dr, v1.x, bb1.x), 0.f);
            v1.y = fmaxf(fmaf(dr, v1.y, bb1.y), 0.f);
            v1.z = fmaxf(fmaf(dr, v1.z, bb1.z), 0.f);
            v1.w = fmaxf(fmaf(dr, v1.w, bb1.w), 0.f);
        }
        *(float4*)&xs[r][c]     = v0;
        *(float4*)&xs[r][c + 4] = v1;
    }
    __syncthreads();

    const int rr = (tid >> 5) << 1;      // 0,2,...,14
    const int c4 = (tid & 31) << 2;      // 0,4,...,124
    float4 a0 = {0.f, 0.f, 0.f, 0.f};
    float4 a1 = {0.f, 0.f, 0.f, 0.f};

#pragma unroll 8
    for (int k = 0; k < DIM; ++k) {
        const float4 w = *(const float4*)&W[k * DIM + c4];
        const float x0 = xs[rr][k];
        const float x1 = xs[rr + 1][k];
        a0.x = fmaf(x0, w.x, a0.x);
        a0.y = fmaf(x0, w.y, a0.y);
        a0.z = fmaf(x0, w.z, a0.z);
        a0.w = fmaf(x0, w.w, a0.w);
        a1.x = fmaf(x1, w.x, a1.x);
        a1.y = fmaf(x1, w.y, a1.y);
        a1.z = fmaf(x1, w.z, a1.z);
        a1.w = fmaf(x1, w.w, a1.w);
    }

    const float d0 = dinv[row0 + rr];
    const float d1 = dinv[row0 + rr + 1];
    a0.x *= d0; a0.y *= d0; a0.z *= d0; a0.w *= d0;
    a1.x *= d1; a1.y *= d1; a1.z *= d1; a1.w *= d1;

    const int o0 = (row0 + rr) * DIM + c4;
    const int o1 = (row0 + rr + 1) * DIM + c4;
    *(float4*)&out_a[o0] = a0;
    *(float4*)&out_a[o1] = a1;
    *(float4*)&out_b[o0] = a0;
    *(float4*)&out_b[o1] = a1;
}

// ---------------- edge scatter: agg[dst] += hs[src] ----------------
// one wave per edge; lane handles 2 consecutive floats (64*2 = 128)
__global__ void k_scatter(const float* __restrict__ hs, float* __restrict__ agg,
                          const int* __restrict__ src, const int* __restrict__ dst, int E) {
    const int w = (blockIdx.x * blockDim.x + threadIdx.x) >> 6;
    if (w >= E) return;
    const int lane = threadIdx.x & 63;
    int s = src[w];
    int d = dst[w];
    s = __builtin_amdgcn_readfirstlane(s);
    d = __builtin_amdgcn_readfirstlane(d);
    const float2 v = *(const float2*)&hs[s * DIM + (lane << 1)];
    float* ap = &agg[d * DIM + (lane << 1)];
    atomicAdd(ap, v.x);
    atomicAdd(ap + 1, v.y);
}

// ---------------- final: out = dinv[row]*out + b2 (in place) ----------------
__global__ void k_final(float* __restrict__ out, const float* __restrict__ dinv,
                        const float* __restrict__ b2) {
    const int i   = blockIdx.x * blockDim.x + threadIdx.x;  // over NN*32 float4s
    const int row = i >> 5;
    const int c4  = (i & 31) << 2;
    float4 v = *(float4*)&out[row * DIM + c4];
    const float dr = dinv[row];
    const float4 b = *(const float4*)&b2[c4];
    v.x = fmaf(dr, v.x, b.x);
    v.y = fmaf(dr, v.y, b.y);
    v.z = fmaf(dr, v.z, b.z);
    v.w = fmaf(dr, v.w, b.w);
    *(float4*)&out[row * DIM + c4] = v;
}

extern "C" void kernel_launch(void* const* d_in, const int* in_sizes, int n_in,
                              void* d_out, int out_size, void* d_ws, size_t ws_size,
                              hipStream_t stream) {
    const float* x  = (const float*)d_in[0];
    const int*   ei = (const int*)d_in[1];
    const float* W1 = (const float*)d_in[2];
    const float* b1 = (const float*)d_in[3];
    const float* W2 = (const float*)d_in[4];
    const float* b2 = (const float*)d_in[5];
    float* out = (float*)d_out;

    const int E = in_sizes[1] / 2;
    const int* src = ei;        // edge_index[0]
    const int* dst = ei + E;    // edge_index[1]

    char* ws = (char*)d_ws;
    float* dinv = (float*)ws;                                   // NN floats
    float* hs   = (float*)(ws + (1 << 20));                     // NN*DIM floats (51.2 MB)
    float* agg  = (float*)(ws + (1 << 20) + 51200000);          // NN*DIM floats (51.2 MB)

    // degrees
    k_init_deg<<<(NN + 255) / 256, 256, 0, stream>>>(dinv, NN);
    k_count_deg<<<(E + 255) / 256, 256, 0, stream>>>(dinv, dst, E);
    k_dinv<<<(NN + 255) / 256, 256, 0, stream>>>(dinv, NN);

    // layer 1: hs = (x@W1)*dinv ; agg seeded with hs (self-loop)
    k_gemm<0><<<NN / 16, 256, 0, stream>>>(x, W1, dinv, nullptr, hs, agg);
    k_scatter<<<(E + 3) / 4, 256, 0, stream>>>(hs, agg, src, dst, E);

    // layer 2: input transform relu(dinv*t1 + b1) fused into GEMM staging;
    // hs2 -> hs buffer, self-loop seed -> d_out
    k_gemm<1><<<NN / 16, 256, 0, stream>>>(agg, W2, dinv, b1, hs, out);
    k_scatter<<<(E + 3) / 4, 256, 0, stream>>>(hs, out, src, dst, E);

    // out = dinv*t2 + b2
    k_final<<<(NN * 32) / 256, 256, 0, stream>>>(out, dinv, b2);
}

// Round 2
// 853.788 us; speedup vs baseline: 3.4209x; 3.4209x over previous
//
#include <hip/hip_runtime.h>
#include <hip/hip_bf16.h>

#define NN 100000
#define DIM 128

// ---------------- degree histogram ----------------
__global__ void k_zero(int* __restrict__ p, int n) {
    int i = blockIdx.x * blockDim.x + threadIdx.x;
    if (i < n) p[i] = 0;
}

__global__ void k_count(int* __restrict__ deg, const int* __restrict__ dst, int E) {
    int e = blockIdx.x * blockDim.x + threadIdx.x;
    if (e < E) atomicAdd(&deg[dst[e]], 1);
}

__global__ void k_dinv(float* __restrict__ dinv, const int* __restrict__ deg, int n) {
    int i = blockIdx.x * blockDim.x + threadIdx.x;
    if (i < n) dinv[i] = rsqrtf((float)(deg[i] + 1));  // +1 self-loop
}

// ---------------- exclusive scan (single block, 1024 threads) ----------------
__global__ void k_scan(const int* __restrict__ deg, int* __restrict__ rowptr,
                       int* __restrict__ cursor, int n) {
    __shared__ int sums[1024];
    const int t = threadIdx.x;
    const int chunk = (n + 1023) >> 10;
    const int lo = t * chunk;
    const int hi = min(lo + chunk, n);
    int s = 0;
    for (int i = lo; i < hi; ++i) s += deg[i];
    sums[t] = s;
    __syncthreads();
    int v = s;
    for (int d = 1; d < 1024; d <<= 1) {
        int o = (t >= d) ? sums[t - d] : 0;
        __syncthreads();
        v += o;
        sums[t] = v;
        __syncthreads();
    }
    int run = v - s;  // exclusive base
    for (int i = lo; i < hi; ++i) {
        rowptr[i] = run;
        cursor[i] = run;
        run += deg[i];
    }
    if (t == 1023) rowptr[n] = run;
}

// ---------------- CSR fill ----------------
__global__ void k_fill(const int* __restrict__ src, const int* __restrict__ dst,
                       int* __restrict__ cursor, int* __restrict__ csr, int E) {
    int e = blockIdx.x * blockDim.x + threadIdx.x;
    if (e < E) {
        int p = atomicAdd(&cursor[dst[e]], 1);
        csr[p] = src[e];
    }
}

// ---------------- GEMM: out = (transform(in) @ W) * dinv[row] ----------------
// 16 rows/block, 256 threads. Thread computes 2 rows x 4 cols.
template <int RELU_IN>
__global__ void k_gemm(const float* __restrict__ in, const float* __restrict__ W,
                       const float* __restrict__ dinv, const float* __restrict__ bin,
                       float* __restrict__ outp) {
    __shared__ float xs[16][DIM];
    const int row0 = blockIdx.x * 16;
    const int tid  = threadIdx.x;

    {
        const int r = tid >> 4;          // 0..15
        const int c = (tid & 15) << 3;   // 0,8,...,120
        float4 v0 = *(const float4*)&in[(row0 + r) * DIM + c];
        float4 v1 = *(const float4*)&in[(row0 + r) * DIM + c + 4];
        if constexpr (RELU_IN) {
            const float dr = dinv[row0 + r];
            const float4 bb0 = *(const float4*)&bin[c];
            const float4 bb1 = *(const float4*)&bin[c + 4];
            v0.x = fmaxf(fmaf(dr, v0.x, bb0.x), 0.f);
            v0.y = fmaxf(fmaf(dr, v0.y, bb0.y), 0.f);
            v0.z = fmaxf(fmaf(dr, v0.z, bb0.z), 0.f);
            v0.w = fmaxf(fmaf(dr, v0.w, bb0.w), 0.f);
            v1.x = fmaxf(fmaf(dr, v1.x, bb1.x), 0.f);
            v1.y = fmaxf(fmaf(dr, v1.y, bb1.y), 0.f);
            v1.z = fmaxf(fmaf(dr, v1.z, bb1.z), 0.f);
            v1.w = fmaxf(fmaf(dr, v1.w, bb1.w), 0.f);
        }
        *(float4*)&xs[r][c]     = v0;
        *(float4*)&xs[r][c + 4] = v1;
    }
    __syncthreads();

    const int rr = (tid >> 5) << 1;      // 0,2,...,14
    const int c4 = (tid & 31) << 2;      // 0,4,...,124
    float4 a0 = {0.f, 0.f, 0.f, 0.f};
    float4 a1 = {0.f, 0.f, 0.f, 0.f};

#pragma unroll 8
    for (int k = 0; k < DIM; ++k) {
        const float4 w = *(const float4*)&W[k * DIM + c4];
        const float x0 = xs[rr][k];
        const float x1 = xs[rr + 1][k];
        a0.x = fmaf(x0, w.x, a0.x);
        a0.y = fmaf(x0, w.y, a0.y);
        a0.z = fmaf(x0, w.z, a0.z);
        a0.w = fmaf(x0, w.w, a0.w);
        a1.x = fmaf(x1, w.x, a1.x);
        a1.y = fmaf(x1, w.y, a1.y);
        a1.z = fmaf(x1, w.z, a1.z);
        a1.w = fmaf(x1, w.w, a1.w);
    }

    const float d0 = dinv[row0 + rr];
    const float d1 = dinv[row0 + rr + 1];
    a0.x *= d0; a0.y *= d0; a0.z *= d0; a0.w *= d0;
    a1.x *= d1; a1.y *= d1; a1.z *= d1; a1.w *= d1;

    *(float4*)&outp[(row0 + rr) * DIM + c4]     = a0;
    *(float4*)&outp[(row0 + rr + 1) * DIM + c4] = a1;
}

// ---------------- gather: out[n] = hs[n] + sum_{j in CSR row n} hs[csr[j]] ----------------
// one wave per node; lane holds float2 (64*8B = 512B row). No atomics.
// FINAL=1: out[n] = acc*dinv[n] + b2
template <int FINAL>
__global__ void k_gather(const float* __restrict__ hs, float* __restrict__ outp,
                         const int* __restrict__ csr, const int* __restrict__ rowptr,
                         const float* __restrict__ dinv, const float* __restrict__ b2) {
    const int w = (blockIdx.x * blockDim.x + threadIdx.x) >> 6;
    if (w >= NN) return;
    const int lane = threadIdx.x & 63;
    const int off  = lane << 1;

    const int start = __builtin_amdgcn_readfirstlane(rowptr[w]);
    const int end   = __builtin_amdgcn_readfirstlane(rowptr[w + 1]);

    float2 acc0 = *(const float2*)&hs[w * DIM + off];  // self-loop
    float2 acc1 = {0.f, 0.f};

    int j = start;
    for (; j + 1 < end; j += 2) {
        const int s0 = __builtin_amdgcn_readfirstlane(csr[j]);
        const int s1 = __builtin_amdgcn_readfirstlane(csr[j + 1]);
        const float2 v0 = *(const float2*)&hs[s0 * DIM + off];
        const float2 v1 = *(const float2*)&hs[s1 * DIM + off];
        acc0.x += v0.x; acc0.y += v0.y;
        acc1.x += v1.x; acc1.y += v1.y;
    }
    if (j < end) {
        const int s0 = __builtin_amdgcn_readfirstlane(csr[j]);
        const float2 v0 = *(const float2*)&hs[s0 * DIM + off];
        acc0.x += v0.x; acc0.y += v0.y;
    }

    float2 r = {acc0.x + acc1.x, acc0.y + acc1.y};
    if constexpr (FINAL) {
        const float d = dinv[w];
        const float2 b = *(const float2*)&b2[off];
        r.x = fmaf(d, r.x, b.x);
        r.y = fmaf(d, r.y, b.y);
    }
    *(float2*)&outp[w * DIM + off] = r;
}

extern "C" void kernel_launch(void* const* d_in, const int* in_sizes, int n_in,
                              void* d_out, int out_size, void* d_ws, size_t ws_size,
                              hipStream_t stream) {
    const float* x  = (const float*)d_in[0];
    const int*   ei = (const int*)d_in[1];
    const float* W1 = (const float*)d_in[2];
    const float* b1 = (const float*)d_in[3];
    const float* W2 = (const float*)d_in[4];
    const float* b2 = (const float*)d_in[5];
    float* out = (float*)d_out;

    const int E = in_sizes[1] / 2;
    const int* src = ei;        // edge_index[0]
    const int* dst = ei + E;    // edge_index[1]

    char* ws = (char*)d_ws;
    float* dinv   = (float*)(ws);                    // NN floats          (400 KB)
    int*   degi   = (int*)  (ws + (1  << 20));       // NN ints            (400 KB)
    int*   rowptr = (int*)  (ws + (2  << 20));       // NN+1 ints
    int*   cursor = (int*)  (ws + (3  << 20));       // NN ints
    int*   csr    = (int*)  (ws + (4  << 20));       // E ints             (6.4 MB)
    float* hs     = (float*)(ws + (12 << 20));       // NN*DIM floats      (51.2 MB)
    float* agg1   = out;                             // reuse d_out as layer-1 agg

    // ---- CSR build (shared by both layers) ----
    k_zero <<<(NN + 255) / 256, 256, 0, stream>>>(degi, NN);
    k_count<<<(E + 255) / 256, 256, 0, stream>>>(degi, dst, E);
    k_scan <<<1, 1024, 0, stream>>>(degi, rowptr, cursor, NN);
    k_dinv <<<(NN + 255) / 256, 256, 0, stream>>>(dinv, degi, NN);
    k_fill <<<(E + 255) / 256, 256, 0, stream>>>(src, dst, cursor, csr, E);

    // ---- layer 1 ----
    k_gemm<0>  <<<NN / 16, 256, 0, stream>>>(x, W1, dinv, nullptr, hs);
    k_gather<0><<<(NN * 64) / 256, 256, 0, stream>>>(hs, agg1, csr, rowptr, dinv, nullptr);

    // ---- layer 2 ----
    k_gemm<1>  <<<NN / 16, 256, 0, stream>>>(agg1, W2, dinv, b1, hs);
    k_gather<1><<<(NN * 64) / 256, 256, 0, stream>>>(hs, out, csr, rowptr, dinv, b2);
}

// Round 3
// 643.073 us; speedup vs baseline: 4.5418x; 1.3277x over previous
//
#include <hip/hip_runtime.h>
#include <hip/hip_bf16.h>

#define NN 100000
#define DIM 128
#define SCAN_NB ((NN + 255) / 256)   // 391 blocks

// ---------------- degree histogram ----------------
__global__ void k_zero(int* __restrict__ p, int n) {
    int i = blockIdx.x * blockDim.x + threadIdx.x;
    if (i < n) p[i] = 0;
}

__global__ void k_count(int* __restrict__ deg, const int* __restrict__ dst, int E) {
    int e = blockIdx.x * blockDim.x + threadIdx.x;
    if (e < E) atomicAdd(&deg[dst[e]], 1);
}

__global__ void k_dinv(float* __restrict__ dinv, const int* __restrict__ deg, int n) {
    int i = blockIdx.x * blockDim.x + threadIdx.x;
    if (i < n) dinv[i] = rsqrtf((float)(deg[i] + 1));  // +1 self-loop
}

// ---------------- hierarchical exclusive scan ----------------
// phase 1: per-block (256-elem) sums
__global__ void k_scan1(const int* __restrict__ deg, int* __restrict__ bsum, int n) {
    __shared__ int red[256];
    const int t = threadIdx.x;
    const int i = blockIdx.x * 256 + t;
    red[t] = (i < n) ? deg[i] : 0;
    __syncthreads();
    for (int d = 128; d > 0; d >>= 1) {
        if (t < d) red[t] += red[t + d];
        __syncthreads();
    }
    if (t == 0) bsum[blockIdx.x] = red[0];
}

// phase 2: exclusive scan of block sums (nb <= 1024), single block
__global__ void k_scan2(int* __restrict__ bsum, int nb) {
    __shared__ int s[1024];
    const int t = threadIdx.x;
    const int v = (t < nb) ? bsum[t] : 0;
    s[t] = v;
    __syncthreads();
    int acc = v;
    for (int d = 1; d < 1024; d <<= 1) {
        const int o = (t >= d) ? s[t - d] : 0;
        __syncthreads();
        acc += o;
        s[t] = acc;
        __syncthreads();
    }
    if (t < nb) bsum[t] = acc - v;  // exclusive
}

// phase 3: per-block exclusive scan + block offset -> rowptr, cursor
__global__ void k_scan3(const int* __restrict__ deg, const int* __restrict__ bsum,
                        int* __restrict__ rowptr, int* __restrict__ cursor, int n) {
    __shared__ int s[256];
    const int t = threadIdx.x;
    const int i = blockIdx.x * 256 + t;
    const int v = (i < n) ? deg[i] : 0;
    s[t] = v;
    __syncthreads();
    int acc = v;
    for (int d = 1; d < 256; d <<= 1) {
        const int o = (t >= d) ? s[t - d] : 0;
        __syncthreads();
        acc += o;
        s[t] = acc;
        __syncthreads();
    }
    const int ex = acc - v + bsum[blockIdx.x];
    if (i < n) {
        rowptr[i] = ex;
        cursor[i] = ex;
        if (i == n - 1) rowptr[n] = ex + v;
    }
}

// ---------------- CSR fill ----------------
__global__ void k_fill(const int* __restrict__ src, const int* __restrict__ dst,
                       int* __restrict__ cursor, int* __restrict__ csr, int E) {
    int e = blockIdx.x * blockDim.x + threadIdx.x;
    if (e < E) {
        int p = atomicAdd(&cursor[dst[e]], 1);
        csr[p] = src[e];
    }
}

// ---------------- GEMM: out = (transform(in) @ W) * dinv[row] ----------------
// 16 rows/block, 256 threads. Thread computes 2 rows x 4 cols.
template <int RELU_IN>
__global__ void k_gemm(const float* __restrict__ in, const float* __restrict__ W,
                       const float* __restrict__ dinv, const float* __restrict__ bin,
                       float* __restrict__ outp) {
    __shared__ float xs[16][DIM];
    const int row0 = blockIdx.x * 16;
    const int tid  = threadIdx.x;

    {
        const int r = tid >> 4;          // 0..15
        const int c = (tid & 15) << 3;   // 0,8,...,120
        float4 v0 = *(const float4*)&in[(row0 + r) * DIM + c];
        float4 v1 = *(const float4*)&in[(row0 + r) * DIM + c + 4];
        if constexpr (RELU_IN) {
            const float dr = dinv[row0 + r];
            const float4 bb0 = *(const float4*)&bin[c];
            const float4 bb1 = *(const float4*)&bin[c + 4];
            v0.x = fmaxf(fmaf(dr, v0.x, bb0.x), 0.f);
            v0.y = fmaxf(fmaf(dr, v0.y, bb0.y), 0.f);
            v0.z = fmaxf(fmaf(dr, v0.z, bb0.z), 0.f);
            v0.w = fmaxf(fmaf(dr, v0.w, bb0.w), 0.f);
            v1.x = fmaxf(fmaf(dr, v1.x, bb1.x), 0.f);
            v1.y = fmaxf(fmaf(dr, v1.y, bb1.y), 0.f);
            v1.z = fmaxf(fmaf(dr, v1.z, bb1.z), 0.f);
            v1.w = fmaxf(fmaf(dr, v1.w, bb1.w), 0.f);
        }
        *(float4*)&xs[r][c]     = v0;
        *(float4*)&xs[r][c + 4] = v1;
    }
    __syncthreads();

    const int rr = (tid >> 5) << 1;      // 0,2,...,14
    const int c4 = (tid & 31) << 2;      // 0,4,...,124
    float4 a0 = {0.f, 0.f, 0.f, 0.f};
    float4 a1 = {0.f, 0.f, 0.f, 0.f};

#pragma unroll 8
    for (int k = 0; k < DIM; ++k) {
        const float4 w = *(const float4*)&W[k * DIM + c4];
        const float x0 = xs[rr][k];
        const float x1 = xs[rr + 1][k];
        a0.x = fmaf(x0, w.x, a0.x);
        a0.y = fmaf(x0, w.y, a0.y);
        a0.z = fmaf(x0, w.z, a0.z);
        a0.w = fmaf(x0, w.w, a0.w);
        a1.x = fmaf(x1, w.x, a1.x);
        a1.y = fmaf(x1, w.y, a1.y);
        a1.z = fmaf(x1, w.z, a1.z);
        a1.w = fmaf(x1, w.w, a1.w);
    }

    const float d0 = dinv[row0 + rr];
    const float d1 = dinv[row0 + rr + 1];
    a0.x *= d0; a0.y *= d0; a0.z *= d0; a0.w *= d0;
    a1.x *= d1; a1.y *= d1; a1.z *= d1; a1.w *= d1;

    *(float4*)&outp[(row0 + rr) * DIM + c4]     = a0;
    *(float4*)&outp[(row0 + rr + 1) * DIM + c4] = a1;
}

// ---------------- gather: out[n] = hs[n] + sum_{j in CSR row n} hs[csr[j]] ----------------
// one wave per node; lane holds float2 (64*8B = 512B row). No atomics.
// FINAL=1: out[n] = acc*dinv[n] + b2
template <int FINAL>
__global__ void k_gather(const float* __restrict__ hs, float* __restrict__ outp,
                         const int* __restrict__ csr, const int* __restrict__ rowptr,
                         const float* __restrict__ dinv, const float* __restrict__ b2) {
    const int w = (blockIdx.x * blockDim.x + threadIdx.x) >> 6;
    if (w >= NN) return;
    const int lane = threadIdx.x & 63;
    const int off  = lane << 1;

    const int start = __builtin_amdgcn_readfirstlane(rowptr[w]);
    const int end   = __builtin_amdgcn_readfirstlane(rowptr[w + 1]);

    float2 acc0 = *(const float2*)&hs[w * DIM + off];  // self-loop
    float2 acc1 = {0.f, 0.f};

    int j = start;
    for (; j + 1 < end; j += 2) {
        const int s0 = __builtin_amdgcn_readfirstlane(csr[j]);
        const int s1 = __builtin_amdgcn_readfirstlane(csr[j + 1]);
        const float2 v0 = *(const float2*)&hs[s0 * DIM + off];
        const float2 v1 = *(const float2*)&hs[s1 * DIM + off];
        acc0.x += v0.x; acc0.y += v0.y;
        acc1.x += v1.x; acc1.y += v1.y;
    }
    if (j < end) {
        const int s0 = __builtin_amdgcn_readfirstlane(csr[j]);
        const float2 v0 = *(const float2*)&hs[s0 * DIM + off];
        acc0.x += v0.x; acc0.y += v0.y;
    }

    float2 r = {acc0.x + acc1.x, acc0.y + acc1.y};
    if constexpr (FINAL) {
        const float d = dinv[w];
        const float2 b = *(const float2*)&b2[off];
        r.x = fmaf(d, r.x, b.x);
        r.y = fmaf(d, r.y, b.y);
    }
    *(float2*)&outp[w * DIM + off] = r;
}

extern "C" void kernel_launch(void* const* d_in, const int* in_sizes, int n_in,
                              void* d_out, int out_size, void* d_ws, size_t ws_size,
                              hipStream_t stream) {
    const float* x  = (const float*)d_in[0];
    const int*   ei = (const int*)d_in[1];
    const float* W1 = (const float*)d_in[2];
    const float* b1 = (const float*)d_in[3];
    const float* W2 = (const float*)d_in[4];
    const float* b2 = (const float*)d_in[5];
    float* out = (float*)d_out;

    const int E = in_sizes[1] / 2;
    const int* src = ei;        // edge_index[0]
    const int* dst = ei + E;    // edge_index[1]

    char* ws = (char*)d_ws;
    float* dinv   = (float*)(ws);                    // NN floats          (400 KB)
    int*   degi   = (int*)  (ws + (1  << 20));       // NN ints            (400 KB)
    int*   rowptr = (int*)  (ws + (2  << 20));       // NN+1 ints
    int*   cursor = (int*)  (ws + (3  << 20));       // NN ints
    int*   bsum   = (int*)  (ws + (3  << 20) + 524288);  // SCAN_NB ints
    int*   csr    = (int*)  (ws + (4  << 20));       // E ints             (6.4 MB)
    float* hs     = (float*)(ws + (12 << 20));       // NN*DIM floats      (51.2 MB)
    float* agg1   = out;                             // reuse d_out as layer-1 agg

    // ---- CSR build (shared by both layers) ----
    k_zero <<<(NN + 255) / 256, 256, 0, stream>>>(degi, NN);
    k_count<<<(E + 255) / 256, 256, 0, stream>>>(degi, dst, E);
    k_scan1<<<SCAN_NB, 256, 0, stream>>>(degi, bsum, NN);
    k_scan2<<<1, 1024, 0, stream>>>(bsum, SCAN_NB);
    k_scan3<<<SCAN_NB, 256, 0, stream>>>(degi, bsum, rowptr, cursor, NN);
    k_dinv <<<(NN + 255) / 256, 256, 0, stream>>>(dinv, degi, NN);
    k_fill <<<(E + 255) / 256, 256, 0, stream>>>(src, dst, cursor, csr, E);

    // ---- layer 1 ----
    k_gemm<0>  <<<NN / 16, 256, 0, stream>>>(x, W1, dinv, nullptr, hs);
    k_gather<0><<<(NN * 64) / 256, 256, 0, stream>>>(hs, agg1, csr, rowptr, dinv, nullptr);

    // ---- layer 2 ----
    k_gemm<1>  <<<NN / 16, 256, 0, stream>>>(agg1, W2, dinv, b1, hs);
    k_gather<1><<<(NN * 64) / 256, 256, 0, stream>>>(hs, out, csr, rowptr, dinv, b2);
}

// Round 4
// 481.555 us; speedup vs baseline: 6.0652x; 1.3354x over previous
//
#include <hip/hip_runtime.h>
#include <hip/hip_bf16.h>

#define NN 100000
#define DIM 128
#define NB 391            // dst buckets of 256 nodes: (NN+255)>>8
#define BCAP 5120         // bucket capacity: lambda=4096, +16 sigma
#define SCAN_NB 391       // scan blocks of 256

// ---------------- tiny zero ----------------
__global__ void k_zero(int* __restrict__ p, int n) {
    int i = blockIdx.x * blockDim.x + threadIdx.x;
    if (i < n) p[i] = 0;
}

// ---------------- Phase A: bin edges by dst>>8, packed src|(dst&255)<<17 ----------------
__global__ void k_binA(const int* __restrict__ src, const int* __restrict__ dst,
                       int* __restrict__ bcur, int* __restrict__ binbuf, int E) {
    __shared__ int hist[NB];
    __shared__ int base[NB];
    const int t = threadIdx.x;
    for (int b = t; b < NB; b += 256) hist[b] = 0;
    __syncthreads();

    const int e0 = blockIdx.x * 4096;
    int mys[16], myd[16];
#pragma unroll
    for (int i = 0; i < 16; ++i) {
        const int e = e0 + i * 256 + t;
        int d = -1, s = 0;
        if (e < E) {
            d = dst[e];
            s = src[e];
            atomicAdd(&hist[d >> 8], 1);
        }
        mys[i] = s;
        myd[i] = d;
    }
    __syncthreads();

    for (int b = t; b < NB; b += 256) {
        const int h = hist[b];
        base[b] = h ? atomicAdd(&bcur[b], h) : 0;
    }
    __syncthreads();
    for (int b = t; b < NB; b += 256) hist[b] = 0;  // reuse as local cursor
    __syncthreads();

#pragma unroll
    for (int i = 0; i < 16; ++i) {
        const int d = myd[i];
        if (d >= 0) {
            const int b = d >> 8;
            const int loc = atomicAdd(&hist[b], 1);
            const int p = base[b] + loc;
            if (p < BCAP) binbuf[b * BCAP + p] = mys[i] | ((d & 255) << 17);
        }
    }
}

// ---------------- Phase B1: per-bucket degree count (LDS hist, coalesced store) ----------------
__global__ void k_binCount(const int* __restrict__ bcur, const int* __restrict__ binbuf,
                           int* __restrict__ degi) {
    __shared__ int cnt[256];
    const int b = blockIdx.x;
    const int t = threadIdx.x;
    cnt[t] = 0;
    __syncthreads();
    const int n = min(bcur[b], BCAP);
    const int* p = &binbuf[b * BCAP];
    for (int i = t; i < n; i += 256) atomicAdd(&cnt[p[i] >> 17], 1);
    __syncthreads();
    const int node = b * 256 + t;
    if (node < NN) degi[node] = cnt[t];
}

// ---------------- hierarchical exclusive scan ----------------
__global__ void k_scan1(const int* __restrict__ deg, int* __restrict__ bsum, int n) {
    __shared__ int red[256];
    const int t = threadIdx.x;
    const int i = blockIdx.x * 256 + t;
    red[t] = (i < n) ? deg[i] : 0;
    __syncthreads();
    for (int d = 128; d > 0; d >>= 1) {
        if (t < d) red[t] += red[t + d];
        __syncthreads();
    }
    if (t == 0) bsum[blockIdx.x] = red[0];
}

__global__ void k_scan2(int* __restrict__ bsum, int nb) {
    __shared__ int s[1024];
    const int t = threadIdx.x;
    const int v = (t < nb) ? bsum[t] : 0;
    s[t] = v;
    __syncthreads();
    int acc = v;
    for (int d = 1; d < 1024; d <<= 1) {
        const int o = (t >= d) ? s[t - d] : 0;
        __syncthreads();
        acc += o;
        s[t] = acc;
        __syncthreads();
    }
    if (t < nb) bsum[t] = acc - v;  // exclusive
}

// phase 3 + fused dinv
__global__ void k_scan3d(const int* __restrict__ deg, const int* __restrict__ bsum,
                         int* __restrict__ rowptr, float* __restrict__ dinv, int n) {
    __shared__ int s[256];
    const int t = threadIdx.x;
    const int i = blockIdx.x * 256 + t;
    const int v = (i < n) ? deg[i] : 0;
    s[t] = v;
    __syncthreads();
    int acc = v;
    for (int d = 1; d < 256; d <<= 1) {
        const int o = (t >= d) ? s[t - d] : 0;
        __syncthreads();
        acc += o;
        s[t] = acc;
        __syncthreads();
    }
    const int ex = acc - v + bsum[blockIdx.x];
    if (i < n) {
        rowptr[i] = ex;
        dinv[i] = rsqrtf((float)(v + 1));  // +1 self-loop
        if (i == n - 1) rowptr[n] = ex + v;
    }
}

// ---------------- fused: fill-CSR blocks [0,NB) + GEMM1 blocks [NB, NB+NN/16) ----------------
// fill: LDS cursors from rowptr; csr writes confined to ~16KB contiguous region per bucket.
// gemm: out = (in @ W) * dinv[row]
__global__ void k_fill_gemm(const float* __restrict__ in, const float* __restrict__ W,
                            const float* __restrict__ dinv, float* __restrict__ outp,
                            const int* __restrict__ rowptr, const int* __restrict__ bcur,
                            const int* __restrict__ binbuf, int* __restrict__ csr) {
    __shared__ float xs[16][DIM];
    __shared__ int cur[256];
    const int t = threadIdx.x;

    if (blockIdx.x < NB) {
        // ---- CSR fill for bucket b ----
        const int b = blockIdx.x;
        const int node = b * 256 + t;
        cur[t] = (node < NN) ? rowptr[node] : 0;
        __syncthreads();
        const int n = min(bcur[b], BCAP);
        const int* p = &binbuf[b * BCAP];
        for (int i = t; i < n; i += 256) {
            const int v = p[i];
            const int pos = atomicAdd(&cur[v >> 17], 1);
            csr[pos] = v & 0x1FFFF;
        }
        return;
    }

    // ---- GEMM1 tile ----
    const int row0 = (blockIdx.x - NB) * 16;
    {
        const int r = t >> 4;
        const int c = (t & 15) << 3;
        float4 v0 = *(const float4*)&in[(row0 + r) * DIM + c];
        float4 v1 = *(const float4*)&in[(row0 + r) * DIM + c + 4];
        *(float4*)&xs[r][c]     = v0;
        *(float4*)&xs[r][c + 4] = v1;
    }
    __syncthreads();

    const int rr = (t >> 5) << 1;
    const int c4 = (t & 31) << 2;
    float4 a0 = {0.f, 0.f, 0.f, 0.f};
    float4 a1 = {0.f, 0.f, 0.f, 0.f};

#pragma unroll 8
    for (int k = 0; k < DIM; ++k) {
        const float4 w = *(const float4*)&W[k * DIM + c4];
        const float x0 = xs[rr][k];
        const float x1 = xs[rr + 1][k];
        a0.x = fmaf(x0, w.x, a0.x);
        a0.y = fmaf(x0, w.y, a0.y);
        a0.z = fmaf(x0, w.z, a0.z);
        a0.w = fmaf(x0, w.w, a0.w);
        a1.x = fmaf(x1, w.x, a1.x);
        a1.y = fmaf(x1, w.y, a1.y);
        a1.z = fmaf(x1, w.z, a1.z);
        a1.w = fmaf(x1, w.w, a1.w);
    }

    const float d0 = dinv[row0 + rr];
    const float d1 = dinv[row0 + rr + 1];
    a0.x *= d0; a0.y *= d0; a0.z *= d0; a0.w *= d0;
    a1.x *= d1; a1.y *= d1; a1.z *= d1; a1.w *= d1;

    *(float4*)&outp[(row0 + rr) * DIM + c4]     = a0;
    *(float4*)&outp[(row0 + rr + 1) * DIM + c4] = a1;
}

// ---------------- standalone GEMM2: out = (relu(dinv*in + b1) @ W) * dinv[row] ----------------
__global__ void k_gemm2(const float* __restrict__ in, const float* __restrict__ W,
                        const float* __restrict__ dinv, const float* __restrict__ bin,
                        float* __restrict__ outp) {
    __shared__ float xs[16][DIM];
    const int row0 = blockIdx.x * 16;
    const int tid  = threadIdx.x;

    {
        const int r = tid >> 4;
        const int c = (tid & 15) << 3;
        float4 v0 = *(const float4*)&in[(row0 + r) * DIM + c];
        float4 v1 = *(const float4*)&in[(row0 + r) * DIM + c + 4];
        const float dr = dinv[row0 + r];
        const float4 bb0 = *(const float4*)&bin[c];
        const float4 bb1 = *(const float4*)&bin[c + 4];
        v0.x = fmaxf(fmaf(dr, v0.x, bb0.x), 0.f);
        v0.y = fmaxf(fmaf(dr, v0.y, bb0.y), 0.f);
        v0.z = fmaxf(fmaf(dr, v0.z, bb0.z), 0.f);
        v0.w = fmaxf(fmaf(dr, v0.w, bb0.w), 0.f);
        v1.x = fmaxf(fmaf(dr, v1.x, bb1.x), 0.f);
        v1.y = fmaxf(fmaf(dr, v1.y, bb1.y), 0.f);
        v1.z = fmaxf(fmaf(dr, v1.z, bb1.z), 0.f);
        v1.w = fmaxf(fmaf(dr, v1.w, bb1.w), 0.f);
        *(float4*)&xs[r][c]     = v0;
        *(float4*)&xs[r][c + 4] = v1;
    }
    __syncthreads();

    const int rr = (tid >> 5) << 1;
    const int c4 = (tid & 31) << 2;
    float4 a0 = {0.f, 0.f, 0.f, 0.f};
    float4 a1 = {0.f, 0.f, 0.f, 0.f};

#pragma unroll 8
    for (int k = 0; k < DIM; ++k) {
        const float4 w = *(const float4*)&W[k * DIM + c4];
        const float x0 = xs[rr][k];
        const float x1 = xs[rr + 1][k];
        a0.x = fmaf(x0, w.x, a0.x);
        a0.y = fmaf(x0, w.y, a0.y);
        a0.z = fmaf(x0, w.z, a0.z);
        a0.w = fmaf(x0, w.w, a0.w);
        a1.x = fmaf(x1, w.x, a1.x);
        a1.y = fmaf(x1, w.y, a1.y);
        a1.z = fmaf(x1, w.z, a1.z);
        a1.w = fmaf(x1, w.w, a1.w);
    }

    const float d0 = dinv[row0 + rr];
    const float d1 = dinv[row0 + rr + 1];
    a0.x *= d0; a0.y *= d0; a0.z *= d0; a0.w *= d0;
    a1.x *= d1; a1.y *= d1; a1.z *= d1; a1.w *= d1;

    *(float4*)&outp[(row0 + rr) * DIM + c4]     = a0;
    *(float4*)&outp[(row0 + rr + 1) * DIM + c4] = a1;
}

// ---------------- gather: out[n] = hs[n] + sum_{j in CSR row n} hs[csr[j]] ----------------
template <int FINAL>
__global__ void k_gather(const float* __restrict__ hs, float* __restrict__ outp,
                         const int* __restrict__ csr, const int* __restrict__ rowptr,
                         const float* __restrict__ dinv, const float* __restrict__ b2) {
    const int w = (blockIdx.x * blockDim.x + threadIdx.x) >> 6;
    if (w >= NN) return;
    const int lane = threadIdx.x & 63;
    const int off  = lane << 1;

    const int start = __builtin_amdgcn_readfirstlane(rowptr[w]);
    const int end   = __builtin_amdgcn_readfirstlane(rowptr[w + 1]);

    float2 acc0 = *(const float2*)&hs[w * DIM + off];  // self-loop
    float2 acc1 = {0.f, 0.f};

    int j = start;
    for (; j + 1 < end; j += 2) {
        const int s0 = __builtin_amdgcn_readfirstlane(csr[j]);
        const int s1 = __builtin_amdgcn_readfirstlane(csr[j + 1]);
        const float2 v0 = *(const float2*)&hs[s0 * DIM + off];
        const float2 v1 = *(const float2*)&hs[s1 * DIM + off];
        acc0.x += v0.x; acc0.y += v0.y;
        acc1.x += v1.x; acc1.y += v1.y;
    }
    if (j < end) {
        const int s0 = __builtin_amdgcn_readfirstlane(csr[j]);
        const float2 v0 = *(const float2*)&hs[s0 * DIM + off];
        acc0.x += v0.x; acc0.y += v0.y;
    }

    float2 r = {acc0.x + acc1.x, acc0.y + acc1.y};
    if constexpr (FINAL) {
        const float d = dinv[w];
        const float2 b = *(const float2*)&b2[off];
        r.x = fmaf(d, r.x, b.x);
        r.y = fmaf(d, r.y, b.y);
    }
    *(float2*)&outp[w * DIM + off] = r;
}

extern "C" void kernel_launch(void* const* d_in, const int* in_sizes, int n_in,
                              void* d_out, int out_size, void* d_ws, size_t ws_size,
                              hipStream_t stream) {
    const float* x  = (const float*)d_in[0];
    const int*   ei = (const int*)d_in[1];
    const float* W1 = (const float*)d_in[2];
    const float* b1 = (const float*)d_in[3];
    const float* W2 = (const float*)d_in[4];
    const float* b2 = (const float*)d_in[5];
    float* out = (float*)d_out;

    const int E = in_sizes[1] / 2;
    const int* src = ei;        // edge_index[0]
    const int* dst = ei + E;    // edge_index[1]

    char* ws = (char*)d_ws;
    float* dinv   = (float*)(ws);                        // NN floats
    int*   degi   = (int*)  (ws + (1  << 20));           // NN ints
    int*   rowptr = (int*)  (ws + (2  << 20));           // NN+1 ints
    int*   bsum   = (int*)  (ws + (3  << 20));           // SCAN_NB ints
    int*   bcur   = (int*)  (ws + (3  << 20) + 65536);   // NB ints
    int*   csr    = (int*)  (ws + (4  << 20));           // E ints (6.4 MB)
    int*   binbuf = (int*)  (ws + (11 << 20));           // NB*BCAP ints (8.0 MB)
    float* hs     = (float*)(ws + (20 << 20));           // NN*DIM floats (51.2 MB)
    float* agg1   = out;                                 // reuse d_out as layer-1 agg

    const int ABLK = (E + 4095) / 4096;                  // 391

    // ---- CSR build (all atomics in LDS; global writes cache-clustered) ----
    k_zero    <<<(NB + 255) / 256, 256, 0, stream>>>(bcur, NB);
    k_binA    <<<ABLK, 256, 0, stream>>>(src, dst, bcur, binbuf, E);
    k_binCount<<<NB, 256, 0, stream>>>(bcur, binbuf, degi);
    k_scan1   <<<SCAN_NB, 256, 0, stream>>>(degi, bsum, NN);
    k_scan2   <<<1, 1024, 0, stream>>>(bsum, SCAN_NB);
    k_scan3d  <<<SCAN_NB, 256, 0, stream>>>(degi, bsum, rowptr, dinv, NN);

    // ---- fill CSR (391 blocks) + GEMM1 (6250 blocks) fused ----
    k_fill_gemm<<<NB + NN / 16, 256, 0, stream>>>(x, W1, dinv, hs, rowptr, bcur, binbuf, csr);
    k_gather<0><<<(NN * 64) / 256, 256, 0, stream>>>(hs, agg1, csr, rowptr, dinv, nullptr);

    // ---- layer 2 ----
    k_gemm2    <<<NN / 16, 256, 0, stream>>>(agg1, W2, dinv, b1, hs);
    k_gather<1><<<(NN * 64) / 256, 256, 0, stream>>>(hs, out, csr, rowptr, dinv, b2);
}

// Round 5
// 386.799 us; speedup vs baseline: 7.5510x; 1.2450x over previous
//
#include <hip/hip_runtime.h>
#include <hip/hip_bf16.h>

#define NN 100000
#define DIM 128
#define NB 391            // dst buckets of 256 nodes: (NN+255)>>8
#define BCAP 5120         // bucket capacity: lambda=4096, +16 sigma
#define SCAN_NB 391       // scan blocks of 256
#define GTILES ((NN + 63) / 64)   // 1563 row-tiles for the GEMM

// ---------------- tiny zero ----------------
__global__ void k_zero(int* __restrict__ p, int n) {
    int i = blockIdx.x * blockDim.x + threadIdx.x;
    if (i < n) p[i] = 0;
}

// ---------------- Phase A: bin edges by dst>>8, packed src|(dst&255)<<17 ----------------
__global__ void k_binA(const int* __restrict__ src, const int* __restrict__ dst,
                       int* __restrict__ bcur, int* __restrict__ binbuf, int E) {
    __shared__ int hist[NB];
    __shared__ int base[NB];
    const int t = threadIdx.x;
    for (int b = t; b < NB; b += 256) hist[b] = 0;
    __syncthreads();

    const int e0 = blockIdx.x * 4096;
    int mys[16], myd[16];
#pragma unroll
    for (int i = 0; i < 16; ++i) {
        const int e = e0 + i * 256 + t;
        int d = -1, s = 0;
        if (e < E) {
            d = dst[e];
            s = src[e];
            atomicAdd(&hist[d >> 8], 1);
        }
        mys[i] = s;
        myd[i] = d;
    }
    __syncthreads();

    for (int b = t; b < NB; b += 256) {
        const int h = hist[b];
        base[b] = h ? atomicAdd(&bcur[b], h) : 0;
    }
    __syncthreads();
    for (int b = t; b < NB; b += 256) hist[b] = 0;  // reuse as local cursor
    __syncthreads();

#pragma unroll
    for (int i = 0; i < 16; ++i) {
        const int d = myd[i];
        if (d >= 0) {
            const int b = d >> 8;
            const int loc = atomicAdd(&hist[b], 1);
            const int p = base[b] + loc;
            if (p < BCAP) binbuf[b * BCAP + p] = mys[i] | ((d & 255) << 17);
        }
    }
}

// ---------------- Phase B1: per-bucket degree count ----------------
__global__ void k_binCount(const int* __restrict__ bcur, const int* __restrict__ binbuf,
                           int* __restrict__ degi) {
    __shared__ int cnt[256];
    const int b = blockIdx.x;
    const int t = threadIdx.x;
    cnt[t] = 0;
    __syncthreads();
    const int n = min(bcur[b], BCAP);
    const int* p = &binbuf[b * BCAP];
    for (int i = t; i < n; i += 256) atomicAdd(&cnt[p[i] >> 17], 1);
    __syncthreads();
    const int node = b * 256 + t;
    if (node < NN) degi[node] = cnt[t];
}

// ---------------- hierarchical exclusive scan ----------------
__global__ void k_scan1(const int* __restrict__ deg, int* __restrict__ bsum, int n) {
    __shared__ int red[256];
    const int t = threadIdx.x;
    const int i = blockIdx.x * 256 + t;
    red[t] = (i < n) ? deg[i] : 0;
    __syncthreads();
    for (int d = 128; d > 0; d >>= 1) {
        if (t < d) red[t] += red[t + d];
        __syncthreads();
    }
    if (t == 0) bsum[blockIdx.x] = red[0];
}

__global__ void k_scan2(int* __restrict__ bsum, int nb) {
    __shared__ int s[1024];
    const int t = threadIdx.x;
    const int v = (t < nb) ? bsum[t] : 0;
    s[t] = v;
    __syncthreads();
    int acc = v;
    for (int d = 1; d < 1024; d <<= 1) {
        const int o = (t >= d) ? s[t - d] : 0;
        __syncthreads();
        acc += o;
        s[t] = acc;
        __syncthreads();
    }
    if (t < nb) bsum[t] = acc - v;  // exclusive
}

__global__ void k_scan3d(const int* __restrict__ deg, const int* __restrict__ bsum,
                         int* __restrict__ rowptr, float* __restrict__ dinv, int n) {
    __shared__ int s[256];
    const int t = threadIdx.x;
    const int i = blockIdx.x * 256 + t;
    const int v = (i < n) ? deg[i] : 0;
    s[t] = v;
    __syncthreads();
    int acc = v;
    for (int d = 1; d < 256; d <<= 1) {
        const int o = (t >= d) ? s[t - d] : 0;
        __syncthreads();
        acc += o;
        s[t] = acc;
        __syncthreads();
    }
    const int ex = acc - v + bsum[blockIdx.x];
    if (i < n) {
        rowptr[i] = ex;
        dinv[i] = rsqrtf((float)(v + 1));  // +1 self-loop
        if (i == n - 1) rowptr[n] = ex + v;
    }
}

// ---------------- register-tiled GEMM (+optional fused CSR-fill blocks) ----------------
// out = (transform(in) @ W) * dinv[row]; transform = relu(dinv*in + bin) if RELU_IN.
// Tile: 64 rows x 128 cols; thread = 8 rows x 4 cols; K staged in 32-wide LDS tiles.
template <int RELU_IN, int FILL>
__global__ void k_gemm(const float* __restrict__ in, const float* __restrict__ W,
                       const float* __restrict__ dinv, const float* __restrict__ bin,
                       float* __restrict__ outp, const int* __restrict__ rowptr,
                       const int* __restrict__ bcur, const int* __restrict__ binbuf,
                       int* __restrict__ csr) {
    __shared__ float wt[32][DIM];   // 16 KB: W k-tile
    __shared__ float xt[64][32];    // 8 KB:  x tile
    __shared__ int cur[256];        // fill cursors
    const int t = threadIdx.x;

    if (FILL && blockIdx.x < NB) {
        // ---- CSR fill for bucket b (LDS cursors; writes land in one ~16KB region) ----
        const int b = blockIdx.x;
        const int node = b * 256 + t;
        cur[t] = (node < NN) ? rowptr[node] : 0;
        __syncthreads();
        const int n = min(bcur[b], BCAP);
        const int* p = &binbuf[b * BCAP];
        for (int i = t; i < n; i += 256) {
            const int v = p[i];
            const int pos = atomicAdd(&cur[v >> 17], 1);
            csr[pos] = v & 0x1FFFF;
        }
        return;
    }

    const int tile = blockIdx.x - (FILL ? NB : 0);
    const int row0 = tile * 64;
    const int g  = t >> 5;          // 0..7
    const int r0 = g << 3;          // thread's rows r0..r0+7 (within tile)
    const int c4 = (t & 31) << 2;   // thread's cols c4..c4+3

    float4 acc[8] = {};

    for (int kt = 0; kt < DIM; kt += 32) {
        // stage W[kt..kt+31][0..127]: 4 float4 per thread, coalesced
#pragma unroll
        for (int j = 0; j < 4; ++j) {
            const int i = t + j * 256;
            const int kr = i >> 5;
            const int kc = (i & 31) << 2;
            *(float4*)&wt[kr][kc] = *(const float4*)&W[(kt + kr) * DIM + kc];
        }
        // stage x[row0..row0+63][kt..kt+31]: 2 float4 per thread, coalesced
#pragma unroll
        for (int j = 0; j < 2; ++j) {
            const int i = t + j * 256;       // 0..511
            const int r = i >> 3;            // 0..63
            const int kc = (i & 7) << 2;     // 0..28
            const int row = row0 + r;
            float4 v = {0.f, 0.f, 0.f, 0.f};
            if (row < NN) v = *(const float4*)&in[row * DIM + kt + kc];
            if constexpr (RELU_IN) {
                const float dr = dinv[row < NN ? row : 0];
                const float4 bb = *(const float4*)&bin[kt + kc];
                v.x = fmaxf(fmaf(dr, v.x, bb.x), 0.f);
                v.y = fmaxf(fmaf(dr, v.y, bb.y), 0.f);
                v.z = fmaxf(fmaf(dr, v.z, bb.z), 0.f);
                v.w = fmaxf(fmaf(dr, v.w, bb.w), 0.f);
            }
            *(float4*)&xt[r][kc] = v;
        }
        __syncthreads();

#pragma unroll
        for (int kk = 0; kk < 32; kk += 4) {
            const float4 w0 = *(const float4*)&wt[kk][c4];
            const float4 w1 = *(const float4*)&wt[kk + 1][c4];
            const float4 w2 = *(const float4*)&wt[kk + 2][c4];
            const float4 w3 = *(const float4*)&wt[kk + 3][c4];
#pragma unroll
            for (int i = 0; i < 8; ++i) {
                const float4 xv = *(const float4*)&xt[r0 + i][kk];
                acc[i].x = fmaf(xv.x, w0.x, fmaf(xv.y, w1.x, fmaf(xv.z, w2.x, fmaf(xv.w, w3.x, acc[i].x))));
                acc[i].y = fmaf(xv.x, w0.y, fmaf(xv.y, w1.y, fmaf(xv.z, w2.y, fmaf(xv.w, w3.y, acc[i].y))));
                acc[i].z = fmaf(xv.x, w0.z, fmaf(xv.y, w1.z, fmaf(xv.z, w2.z, fmaf(xv.w, w3.z, acc[i].z))));
                acc[i].w = fmaf(xv.x, w0.w, fmaf(xv.y, w1.w, fmaf(xv.z, w2.w, fmaf(xv.w, w3.w, acc[i].w))));
            }
        }
        __syncthreads();
    }

#pragma unroll
    for (int i = 0; i < 8; ++i) {
        const int row = row0 + r0 + i;
        if (row < NN) {
            const float d = dinv[row];
            float4 a = acc[i];
            a.x *= d; a.y *= d; a.z *= d; a.w *= d;
            *(float4*)&outp[row * DIM + c4] = a;
        }
    }
}

// ---------------- gather: out[n] = hs[n] + sum_{j in CSR row n} hs[csr[j]] ----------------
template <int FINAL>
__global__ void k_gather(const float* __restrict__ hs, float* __restrict__ outp,
                         const int* __restrict__ csr, const int* __restrict__ rowptr,
                         const float* __restrict__ dinv, const float* __restrict__ b2) {
    const int w = (blockIdx.x * blockDim.x + threadIdx.x) >> 6;
    if (w >= NN) return;
    const int lane = threadIdx.x & 63;
    const int off  = lane << 1;

    const int start = __builtin_amdgcn_readfirstlane(rowptr[w]);
    const int end   = __builtin_amdgcn_readfirstlane(rowptr[w + 1]);

    float2 acc0 = *(const float2*)&hs[w * DIM + off];  // self-loop
    float2 acc1 = {0.f, 0.f};

    int j = start;
    for (; j + 1 < end; j += 2) {
        const int s0 = __builtin_amdgcn_readfirstlane(csr[j]);
        const int s1 = __builtin_amdgcn_readfirstlane(csr[j + 1]);
        const float2 v0 = *(const float2*)&hs[s0 * DIM + off];
        const float2 v1 = *(const float2*)&hs[s1 * DIM + off];
        acc0.x += v0.x; acc0.y += v0.y;
        acc1.x += v1.x; acc1.y += v1.y;
    }
    if (j < end) {
        const int s0 = __builtin_amdgcn_readfirstlane(csr[j]);
        const float2 v0 = *(const float2*)&hs[s0 * DIM + off];
        acc0.x += v0.x; acc0.y += v0.y;
    }

    float2 r = {acc0.x + acc1.x, acc0.y + acc1.y};
    if constexpr (FINAL) {
        const float d = dinv[w];
        const float2 b = *(const float2*)&b2[off];
        r.x = fmaf(d, r.x, b.x);
        r.y = fmaf(d, r.y, b.y);
    }
    *(float2*)&outp[w * DIM + off] = r;
}

extern "C" void kernel_launch(void* const* d_in, const int* in_sizes, int n_in,
                              void* d_out, int out_size, void* d_ws, size_t ws_size,
                              hipStream_t stream) {
    const float* x  = (const float*)d_in[0];
    const int*   ei = (const int*)d_in[1];
    const float* W1 = (const float*)d_in[2];
    const float* b1 = (const float*)d_in[3];
    const float* W2 = (const float*)d_in[4];
    const float* b2 = (const float*)d_in[5];
    float* out = (float*)d_out;

    const int E = in_sizes[1] / 2;
    const int* src = ei;        // edge_index[0]
    const int* dst = ei + E;    // edge_index[1]

    char* ws = (char*)d_ws;
    float* dinv   = (float*)(ws);                        // NN floats
    int*   degi   = (int*)  (ws + (1  << 20));           // NN ints
    int*   rowptr = (int*)  (ws + (2  << 20));           // NN+1 ints
    int*   bsum   = (int*)  (ws + (3  << 20));           // SCAN_NB ints
    int*   bcur   = (int*)  (ws + (3  << 20) + 65536);   // NB ints
    int*   csr    = (int*)  (ws + (4  << 20));           // E ints (6.4 MB)
    int*   binbuf = (int*)  (ws + (11 << 20));           // NB*BCAP ints (8.0 MB)
    float* hs     = (float*)(ws + (20 << 20));           // NN*DIM floats (51.2 MB)
    float* agg1   = out;                                 // reuse d_out as layer-1 agg

    const int ABLK = (E + 4095) / 4096;                  // 391

    // ---- CSR build (all atomics in LDS; global writes cache-clustered) ----
    k_zero    <<<(NB + 255) / 256, 256, 0, stream>>>(bcur, NB);
    k_binA    <<<ABLK, 256, 0, stream>>>(src, dst, bcur, binbuf, E);
    k_binCount<<<NB, 256, 0, stream>>>(bcur, binbuf, degi);
    k_scan1   <<<SCAN_NB, 256, 0, stream>>>(degi, bsum, NN);
    k_scan2   <<<1, 1024, 0, stream>>>(bsum, SCAN_NB);
    k_scan3d  <<<SCAN_NB, 256, 0, stream>>>(degi, bsum, rowptr, dinv, NN);

    // ---- layer 1: fill CSR (391 blocks) + GEMM1 (1563 tiles) fused ----
    k_gemm<0, 1><<<NB + GTILES, 256, 0, stream>>>(x, W1, dinv, nullptr, hs,
                                                  rowptr, bcur, binbuf, csr);
    k_gather<0> <<<(NN * 64) / 256, 256, 0, stream>>>(hs, agg1, csr, rowptr, dinv, nullptr);

    // ---- layer 2 ----
    k_gemm<1, 0><<<GTILES, 256, 0, stream>>>(agg1, W2, dinv, b1, hs,
                                             rowptr, bcur, binbuf, csr);
    k_gather<1> <<<(NN * 64) / 256, 256, 0, stream>>>(hs, out, csr, rowptr, dinv, b2);
}

// Round 6
// 269.837 us; speedup vs baseline: 10.8241x; 1.4335x over previous
//
#include <hip/hip_runtime.h>
#include <hip/hip_bf16.h>
#include <hip/hip_fp16.h>

#define NN 100000
#define DIM 128
#define NB 391            // dst buckets of 256 nodes: (NN+255)>>8
#define BCAP 5120         // bucket capacity: lambda=4096, +16 sigma
#define SCAN_NB 391       // scan blocks of 256
#define GTILES ((NN + 63) / 64)   // 1563 row-tiles for the GEMM

// ---------------- tiny zero ----------------
__global__ void k_zero(int* __restrict__ p, int n) {
    int i = blockIdx.x * blockDim.x + threadIdx.x;
    if (i < n) p[i] = 0;
}

// ---------------- Phase A: bin edges by dst>>8, packed src|(dst&255)<<17 ----------------
__global__ void k_binA(const int* __restrict__ src, const int* __restrict__ dst,
                       int* __restrict__ bcur, int* __restrict__ binbuf, int E) {
    __shared__ int hist[NB];
    __shared__ int base[NB];
    const int t = threadIdx.x;
    for (int b = t; b < NB; b += 256) hist[b] = 0;
    __syncthreads();

    const int e0 = blockIdx.x * 4096;
    int mys[16], myd[16];
#pragma unroll
    for (int i = 0; i < 16; ++i) {
        const int e = e0 + i * 256 + t;
        int d = -1, s = 0;
        if (e < E) {
            d = dst[e];
            s = src[e];
            atomicAdd(&hist[d >> 8], 1);
        }
        mys[i] = s;
        myd[i] = d;
    }
    __syncthreads();

    for (int b = t; b < NB; b += 256) {
        const int h = hist[b];
        base[b] = h ? atomicAdd(&bcur[b], h) : 0;
    }
    __syncthreads();
    for (int b = t; b < NB; b += 256) hist[b] = 0;  // reuse as local cursor
    __syncthreads();

#pragma unroll
    for (int i = 0; i < 16; ++i) {
        const int d = myd[i];
        if (d >= 0) {
            const int b = d >> 8;
            const int loc = atomicAdd(&hist[b], 1);
            const int p = base[b] + loc;
            if (p < BCAP) binbuf[b * BCAP + p] = mys[i] | ((d & 255) << 17);
        }
    }
}

// ---------------- Phase B1: per-bucket degree count ----------------
__global__ void k_binCount(const int* __restrict__ bcur, const int* __restrict__ binbuf,
                           int* __restrict__ degi) {
    __shared__ int cnt[256];
    const int b = blockIdx.x;
    const int t = threadIdx.x;
    cnt[t] = 0;
    __syncthreads();
    const int n = min(bcur[b], BCAP);
    const int* p = &binbuf[b * BCAP];
    for (int i = t; i < n; i += 256) atomicAdd(&cnt[p[i] >> 17], 1);
    __syncthreads();
    const int node = b * 256 + t;
    if (node < NN) degi[node] = cnt[t];
}

// ---------------- hierarchical exclusive scan ----------------
__global__ void k_scan1(const int* __restrict__ deg, int* __restrict__ bsum, int n) {
    __shared__ int red[256];
    const int t = threadIdx.x;
    const int i = blockIdx.x * 256 + t;
    red[t] = (i < n) ? deg[i] : 0;
    __syncthreads();
    for (int d = 128; d > 0; d >>= 1) {
        if (t < d) red[t] += red[t + d];
        __syncthreads();
    }
    if (t == 0) bsum[blockIdx.x] = red[0];
}

__global__ void k_scan2(int* __restrict__ bsum, int nb) {
    __shared__ int s[1024];
    const int t = threadIdx.x;
    const int v = (t < nb) ? bsum[t] : 0;
    s[t] = v;
    __syncthreads();
    int acc = v;
    for (int d = 1; d < 1024; d <<= 1) {
        const int o = (t >= d) ? s[t - d] : 0;
        __syncthreads();
        acc += o;
        s[t] = acc;
        __syncthreads();
    }
    if (t < nb) bsum[t] = acc - v;  // exclusive
}

__global__ void k_scan3d(const int* __restrict__ deg, const int* __restrict__ bsum,
                         int* __restrict__ rowptr, float* __restrict__ dinv, int n) {
    __shared__ int s[256];
    const int t = threadIdx.x;
    const int i = blockIdx.x * 256 + t;
    const int v = (i < n) ? deg[i] : 0;
    s[t] = v;
    __syncthreads();
    int acc = v;
    for (int d = 1; d < 256; d <<= 1) {
        const int o = (t >= d) ? s[t - d] : 0;
        __syncthreads();
        acc += o;
        s[t] = acc;
        __syncthreads();
    }
    const int ex = acc - v + bsum[blockIdx.x];
    if (i < n) {
        rowptr[i] = ex;
        dinv[i] = rsqrtf((float)(v + 1));  // +1 self-loop
        if (i == n - 1) rowptr[n] = ex + v;
    }
}

// ---------------- register-tiled GEMM -> fp16 out (+optional fused CSR-fill) ----------------
// outH = half( (transform(in) @ W) * dinv[row] ).
// IN_HALF=0: in = inF (fp32, layer-1 x), no transform.
// IN_HALF=1: in = inH (fp16 agg), transform = relu(dinv*in + bin).
// Tile: 64 rows x 128 cols; thread = 8 rows x 4 cols; K in 32-wide LDS tiles.
template <int IN_HALF, int FILL>
__global__ void k_gemm(const float* __restrict__ inF, const __half* __restrict__ inH,
                       const float* __restrict__ W, const float* __restrict__ dinv,
                       const float* __restrict__ bin, __half* __restrict__ outH,
                       const int* __restrict__ rowptr, const int* __restrict__ bcur,
                       const int* __restrict__ binbuf, int* __restrict__ csr) {
    __shared__ float wt[32][DIM];   // 16 KB: W k-tile
    __shared__ float xt[64][32];    // 8 KB:  x tile
    __shared__ int cur[256];        // fill cursors
    const int t = threadIdx.x;

    if (FILL && blockIdx.x < NB) {
        // ---- CSR fill for bucket b (LDS cursors; writes land in one ~16KB region) ----
        const int b = blockIdx.x;
        const int node = b * 256 + t;
        cur[t] = (node < NN) ? rowptr[node] : 0;
        __syncthreads();
        const int n = min(bcur[b], BCAP);
        const int* p = &binbuf[b * BCAP];
        for (int i = t; i < n; i += 256) {
            const int v = p[i];
            const int pos = atomicAdd(&cur[v >> 17], 1);
            csr[pos] = v & 0x1FFFF;
        }
        return;
    }

    const int tile = blockIdx.x - (FILL ? NB : 0);
    const int row0 = tile * 64;
    const int g  = t >> 5;          // 0..7
    const int r0 = g << 3;          // rows r0..r0+7 within tile
    const int c4 = (t & 31) << 2;   // cols c4..c4+3

    float4 acc[8] = {};

    for (int kt = 0; kt < DIM; kt += 32) {
        // stage W[kt..kt+31][0..127]
#pragma unroll
        for (int j = 0; j < 4; ++j) {
            const int i = t + j * 256;
            const int kr = i >> 5;
            const int kc = (i & 31) << 2;
            *(float4*)&wt[kr][kc] = *(const float4*)&W[(kt + kr) * DIM + kc];
        }
        // stage x[row0..row0+63][kt..kt+31]
#pragma unroll
        for (int j = 0; j < 2; ++j) {
            const int i = t + j * 256;       // 0..511
            const int r = i >> 3;            // 0..63
            const int kc = (i & 7) << 2;     // 0..28
            const int row = row0 + r;
            float4 v = {0.f, 0.f, 0.f, 0.f};
            if constexpr (IN_HALF) {
                if (row < NN) {
                    const __half2 h0 = *(const __half2*)&inH[row * DIM + kt + kc];
                    const __half2 h1 = *(const __half2*)&inH[row * DIM + kt + kc + 2];
                    const float2 f0 = __half22float2(h0);
                    const float2 f1 = __half22float2(h1);
                    const float dr = dinv[row];
                    const float4 bb = *(const float4*)&bin[kt + kc];
                    v.x = fmaxf(fmaf(dr, f0.x, bb.x), 0.f);
                    v.y = fmaxf(fmaf(dr, f0.y, bb.y), 0.f);
                    v.z = fmaxf(fmaf(dr, f1.x, bb.z), 0.f);
                    v.w = fmaxf(fmaf(dr, f1.y, bb.w), 0.f);
                }
            } else {
                if (row < NN) v = *(const float4*)&inF[row * DIM + kt + kc];
            }
            *(float4*)&xt[r][kc] = v;
        }
        __syncthreads();

#pragma unroll
        for (int kk = 0; kk < 32; kk += 4) {
            const float4 w0 = *(const float4*)&wt[kk][c4];
            const float4 w1 = *(const float4*)&wt[kk + 1][c4];
            const float4 w2 = *(const float4*)&wt[kk + 2][c4];
            const float4 w3 = *(const float4*)&wt[kk + 3][c4];
#pragma unroll
            for (int i = 0; i < 8; ++i) {
                const float4 xv = *(const float4*)&xt[r0 + i][kk];
                acc[i].x = fmaf(xv.x, w0.x, fmaf(xv.y, w1.x, fmaf(xv.z, w2.x, fmaf(xv.w, w3.x, acc[i].x))));
                acc[i].y = fmaf(xv.x, w0.y, fmaf(xv.y, w1.y, fmaf(xv.z, w2.y, fmaf(xv.w, w3.y, acc[i].y))));
                acc[i].z = fmaf(xv.x, w0.z, fmaf(xv.y, w1.z, fmaf(xv.z, w2.z, fmaf(xv.w, w3.z, acc[i].z))));
                acc[i].w = fmaf(xv.x, w0.w, fmaf(xv.y, w1.w, fmaf(xv.z, w2.w, fmaf(xv.w, w3.w, acc[i].w))));
            }
        }
        __syncthreads();
    }

#pragma unroll
    for (int i = 0; i < 8; ++i) {
        const int row = row0 + r0 + i;
        if (row < NN) {
            const float d = dinv[row];
            union { __half2 h2[2]; uint2 u; } pk;
            pk.h2[0] = __floats2half2_rn(acc[i].x * d, acc[i].y * d);
            pk.h2[1] = __floats2half2_rn(acc[i].z * d, acc[i].w * d);
            *(uint2*)&outH[row * DIM + c4] = pk.u;
        }
    }
}

// ---------------- gather (fp16 rows): acc[n] = hs[n] + sum_{j in row n} hs[csr[j]] ----------------
// one wave per node; lane holds half2 (64*4B = 256B row). No atomics.
// FINAL=0: outH[n] = half(acc);  FINAL=1: outF[n] = acc*dinv[n] + b2.
template <int FINAL>
__global__ void k_gather(const __half* __restrict__ hs, __half* __restrict__ outH,
                         float* __restrict__ outF, const int* __restrict__ csr,
                         const int* __restrict__ rowptr, const float* __restrict__ dinv,
                         const float* __restrict__ b2) {
    const int w = (blockIdx.x * blockDim.x + threadIdx.x) >> 6;
    if (w >= NN) return;
    const int lane = threadIdx.x & 63;
    const int off  = lane << 1;    // half index

    const int start = __builtin_amdgcn_readfirstlane(rowptr[w]);
    const int end   = __builtin_amdgcn_readfirstlane(rowptr[w + 1]);

    float2 a0 = __half22float2(*(const __half2*)&hs[w * DIM + off]);  // self-loop
    float2 a1 = {0.f, 0.f}, a2 = {0.f, 0.f}, a3 = {0.f, 0.f};

    int j = start;
    for (; j + 3 < end; j += 4) {
        const int s0 = __builtin_amdgcn_readfirstlane(csr[j]);
        const int s1 = __builtin_amdgcn_readfirstlane(csr[j + 1]);
        const int s2 = __builtin_amdgcn_readfirstlane(csr[j + 2]);
        const int s3 = __builtin_amdgcn_readfirstlane(csr[j + 3]);
        const float2 v0 = __half22float2(*(const __half2*)&hs[s0 * DIM + off]);
        const float2 v1 = __half22float2(*(const __half2*)&hs[s1 * DIM + off]);
        const float2 v2 = __half22float2(*(const __half2*)&hs[s2 * DIM + off]);
        const float2 v3 = __half22float2(*(const __half2*)&hs[s3 * DIM + off]);
        a0.x += v0.x; a0.y += v0.y;
        a1.x += v1.x; a1.y += v1.y;
        a2.x += v2.x; a2.y += v2.y;
        a3.x += v3.x; a3.y += v3.y;
    }
    for (; j < end; ++j) {
        const int s0 = __builtin_amdgcn_readfirstlane(csr[j]);
        const float2 v0 = __half22float2(*(const __half2*)&hs[s0 * DIM + off]);
        a0.x += v0.x; a0.y += v0.y;
    }

    float2 r = {a0.x + a1.x + a2.x + a3.x, a0.y + a1.y + a2.y + a3.y};
    if constexpr (FINAL) {
        const float d = dinv[w];
        const float2 b = *(const float2*)&b2[off];
        r.x = fmaf(d, r.x, b.x);
        r.y = fmaf(d, r.y, b.y);
        *(float2*)&outF[w * DIM + off] = r;
    } else {
        *(__half2*)&outH[w * DIM + off] = __floats2half2_rn(r.x, r.y);
    }
}

extern "C" void kernel_launch(void* const* d_in, const int* in_sizes, int n_in,
                              void* d_out, int out_size, void* d_ws, size_t ws_size,
                              hipStream_t stream) {
    const float* x  = (const float*)d_in[0];
    const int*   ei = (const int*)d_in[1];
    const float* W1 = (const float*)d_in[2];
    const float* b1 = (const float*)d_in[3];
    const float* W2 = (const float*)d_in[4];
    const float* b2 = (const float*)d_in[5];
    float* out = (float*)d_out;

    const int E = in_sizes[1] / 2;
    const int* src = ei;        // edge_index[0]
    const int* dst = ei + E;    // edge_index[1]

    char* ws = (char*)d_ws;
    float*  dinv   = (float*)(ws);                        // NN floats
    int*    degi   = (int*)  (ws + (1  << 20));           // NN ints
    int*    rowptr = (int*)  (ws + (2  << 20));           // NN+1 ints
    int*    bsum   = (int*)  (ws + (3  << 20));           // SCAN_NB ints
    int*    bcur   = (int*)  (ws + (3  << 20) + 65536);   // NB ints
    int*    csr    = (int*)  (ws + (4  << 20));           // E ints (6.4 MB)
    int*    binbuf = (int*)  (ws + (11 << 20));           // NB*BCAP ints (8.0 MB)
    __half* hs     = (__half*)(ws + (20 << 20));          // NN*DIM halfs (25.6 MB)
    __half* agg1   = (__half*)(ws + (47 << 20));          // NN*DIM halfs (25.6 MB)

    const int ABLK = (E + 4095) / 4096;                   // 391

    // ---- CSR build (all atomics in LDS; global writes cache-clustered) ----
    k_zero    <<<(NB + 255) / 256, 256, 0, stream>>>(bcur, NB);
    k_binA    <<<ABLK, 256, 0, stream>>>(src, dst, bcur, binbuf, E);
    k_binCount<<<NB, 256, 0, stream>>>(bcur, binbuf, degi);
    k_scan1   <<<SCAN_NB, 256, 0, stream>>>(degi, bsum, NN);
    k_scan2   <<<1, 1024, 0, stream>>>(bsum, SCAN_NB);
    k_scan3d  <<<SCAN_NB, 256, 0, stream>>>(degi, bsum, rowptr, dinv, NN);

    // ---- layer 1: fill CSR (391 blocks) + GEMM1 (1563 tiles) fused ----
    k_gemm<0, 1><<<NB + GTILES, 256, 0, stream>>>(x, nullptr, W1, dinv, nullptr, hs,
                                                  rowptr, bcur, binbuf, csr);
    k_gather<0> <<<(NN * 64) / 256, 256, 0, stream>>>(hs, agg1, nullptr, csr, rowptr,
                                                      dinv, nullptr);

    // ---- layer 2 ----
    k_gemm<1, 0><<<GTILES, 256, 0, stream>>>(nullptr, agg1, W2, dinv, b1, hs,
                                             rowptr, bcur, binbuf, csr);
    k_gather<1> <<<(NN * 64) / 256, 256, 0, stream>>>(hs, nullptr, out, csr, rowptr,
                                                      dinv, b2);
}

// Round 7
// 236.691 us; speedup vs baseline: 12.3399x; 1.1400x over previous
//
#include <hip/hip_runtime.h>
#include <hip/hip_bf16.h>
#include <hip/hip_fp16.h>

#define NN 100000
#define DIM 128
#define NB 391            // dst buckets of 256 nodes: (NN+255)>>8
#define BCAP 5120         // bucket capacity: lambda=4096, +16 sigma
#define SCAN_NB 391       // scan blocks of 256
#define GTILES ((NN + 63) / 64)   // 1563 row-tiles (64 rows each)

typedef _Float16 f16x8 __attribute__((ext_vector_type(8)));
typedef float f32x4 __attribute__((ext_vector_type(4)));

// ---------------- tiny zero ----------------
__global__ void k_zero(int* __restrict__ p, int n) {
    int i = blockIdx.x * blockDim.x + threadIdx.x;
    if (i < n) p[i] = 0;
}

// ---------------- Phase A: bin edges by dst>>8, packed src|(dst&255)<<17 ----------------
__global__ void k_binA(const int* __restrict__ src, const int* __restrict__ dst,
                       int* __restrict__ bcur, int* __restrict__ binbuf, int E) {
    __shared__ int hist[NB];
    __shared__ int base[NB];
    const int t = threadIdx.x;
    for (int b = t; b < NB; b += 256) hist[b] = 0;
    __syncthreads();

    const int e0 = blockIdx.x * 4096;
    int mys[16], myd[16];
#pragma unroll
    for (int i = 0; i < 16; ++i) {
        const int e = e0 + i * 256 + t;
        int d = -1, s = 0;
        if (e < E) {
            d = dst[e];
            s = src[e];
            atomicAdd(&hist[d >> 8], 1);
        }
        mys[i] = s;
        myd[i] = d;
    }
    __syncthreads();

    for (int b = t; b < NB; b += 256) {
        const int h = hist[b];
        base[b] = h ? atomicAdd(&bcur[b], h) : 0;
    }
    __syncthreads();
    for (int b = t; b < NB; b += 256) hist[b] = 0;  // reuse as local cursor
    __syncthreads();

#pragma unroll
    for (int i = 0; i < 16; ++i) {
        const int d = myd[i];
        if (d >= 0) {
            const int b = d >> 8;
            const int loc = atomicAdd(&hist[b], 1);
            const int p = base[b] + loc;
            if (p < BCAP) binbuf[b * BCAP + p] = mys[i] | ((d & 255) << 17);
        }
    }
}

// ---------------- Phase B1: per-bucket degree count ----------------
__global__ void k_binCount(const int* __restrict__ bcur, const int* __restrict__ binbuf,
                           int* __restrict__ degi) {
    __shared__ int cnt[256];
    const int b = blockIdx.x;
    const int t = threadIdx.x;
    cnt[t] = 0;
    __syncthreads();
    const int n = min(bcur[b], BCAP);
    const int* p = &binbuf[b * BCAP];
    for (int i = t; i < n; i += 256) atomicAdd(&cnt[p[i] >> 17], 1);
    __syncthreads();
    const int node = b * 256 + t;
    if (node < NN) degi[node] = cnt[t];
}

// ---------------- hierarchical exclusive scan ----------------
__global__ void k_scan1(const int* __restrict__ deg, int* __restrict__ bsum, int n) {
    __shared__ int red[256];
    const int t = threadIdx.x;
    const int i = blockIdx.x * 256 + t;
    red[t] = (i < n) ? deg[i] : 0;
    __syncthreads();
    for (int d = 128; d > 0; d >>= 1) {
        if (t < d) red[t] += red[t + d];
        __syncthreads();
    }
    if (t == 0) bsum[blockIdx.x] = red[0];
}

__global__ void k_scan2(int* __restrict__ bsum, int nb) {
    __shared__ int s[1024];
    const int t = threadIdx.x;
    const int v = (t < nb) ? bsum[t] : 0;
    s[t] = v;
    __syncthreads();
    int acc = v;
    for (int d = 1; d < 1024; d <<= 1) {
        const int o = (t >= d) ? s[t - d] : 0;
        __syncthreads();
        acc += o;
        s[t] = acc;
        __syncthreads();
    }
    if (t < nb) bsum[t] = acc - v;  // exclusive
}

__global__ void k_scan3d(const int* __restrict__ deg, const int* __restrict__ bsum,
                         int* __restrict__ rowptr, float* __restrict__ dinv, int n) {
    __shared__ int s[256];
    const int t = threadIdx.x;
    const int i = blockIdx.x * 256 + t;
    const int v = (i < n) ? deg[i] : 0;
    s[t] = v;
    __syncthreads();
    int acc = v;
    for (int d = 1; d < 256; d <<= 1) {
        const int o = (t >= d) ? s[t - d] : 0;
        __syncthreads();
        acc += o;
        s[t] = acc;
        __syncthreads();
    }
    const int ex = acc - v + bsum[blockIdx.x];
    if (i < n) {
        rowptr[i] = ex;
        dinv[i] = rsqrtf((float)(v + 1));  // +1 self-loop
        if (i == n - 1) rowptr[n] = ex + v;
    }
}

// ---------------- MFMA GEMM -> fp16 out (+optional fused CSR-fill) ----------------
// outH = half( (transform(in) @ W) * dinv[row] )
// IN_HALF=0: in = inF (fp32 x), no transform. IN_HALF=1: in = inH fp16, relu(dinv*in+bin).
// Block: 64 rows x 128 cols, 4 waves. Wave w: cols [32w, 32w+32), W-frags held in regs.
// mfma_f32_16x16x32_f16 layouts: A row=l&15, k=8*(l>>4)+j; B col=l&15, k=8*(l>>4)+j;
// D col=l&15, row=4*(l>>4)+reg  (per m89-verified mapping).
template <int IN_HALF, int FILL>
__global__ void k_gemm(const float* __restrict__ inF, const _Float16* __restrict__ inH,
                       const float* __restrict__ W, const float* __restrict__ dinv,
                       const float* __restrict__ bin, _Float16* __restrict__ outH,
                       const int* __restrict__ rowptr, const int* __restrict__ bcur,
                       const int* __restrict__ binbuf, int* __restrict__ csr) {
    __shared__ int cur[256];        // fill cursors (unused in gemm blocks)
    const int t = threadIdx.x;

    if (FILL && blockIdx.x < NB) {
        const int b = blockIdx.x;
        const int node = b * 256 + t;
        cur[t] = (node < NN) ? rowptr[node] : 0;
        __syncthreads();
        const int n = min(bcur[b], BCAP);
        const int* p = &binbuf[b * BCAP];
        for (int i = t; i < n; i += 256) {
            const int v = p[i];
            const int pos = atomicAdd(&cur[v >> 17], 1);
            csr[pos] = v & 0x1FFFF;
        }
        return;
    }

    const int tile = blockIdx.x - (FILL ? NB : 0);
    const int row0 = tile * 64;
    const int wv   = t >> 6;        // wave 0..3
    const int l    = t & 63;
    const int l15  = l & 15;
    const int lk8  = (l >> 4) << 3; // 0,8,16,24
    const int colw = wv << 5;       // wave's col base

    // ---- load wave-private W fragments (once): bf[ct][kt] ----
    f16x8 bf[2][4];
#pragma unroll
    for (int ct = 0; ct < 2; ++ct) {
#pragma unroll
        for (int kt = 0; kt < 4; ++kt) {
            const int n  = colw + ct * 16 + l15;
            const int k0 = kt * 32 + lk8;
            f16x8 v;
#pragma unroll
            for (int j = 0; j < 8; ++j) v[j] = (_Float16)W[(k0 + j) * DIM + n];
            bf[ct][kt] = v;
        }
    }

    f32x4 acc[4][2];
#pragma unroll
    for (int rt = 0; rt < 4; ++rt)
#pragma unroll
        for (int ct = 0; ct < 2; ++ct) acc[rt][ct] = (f32x4){0.f, 0.f, 0.f, 0.f};

#pragma unroll
    for (int rt = 0; rt < 4; ++rt) {
        int row = row0 + rt * 16 + l15;
        row = min(row, NN - 1);
        f16x8 a[4];
#pragma unroll
        for (int kt = 0; kt < 4; ++kt) {
            const int k0 = kt * 32 + lk8;
            if constexpr (IN_HALF) {
                const f16x8 h = *(const f16x8*)&inH[row * DIM + k0];
                const float dr = dinv[row];
                const float4 bb0 = *(const float4*)&bin[k0];
                const float4 bb1 = *(const float4*)&bin[k0 + 4];
                f16x8 v;
                v[0] = (_Float16)fmaxf(fmaf(dr, (float)h[0], bb0.x), 0.f);
                v[1] = (_Float16)fmaxf(fmaf(dr, (float)h[1], bb0.y), 0.f);
                v[2] = (_Float16)fmaxf(fmaf(dr, (float)h[2], bb0.z), 0.f);
                v[3] = (_Float16)fmaxf(fmaf(dr, (float)h[3], bb0.w), 0.f);
                v[4] = (_Float16)fmaxf(fmaf(dr, (float)h[4], bb1.x), 0.f);
                v[5] = (_Float16)fmaxf(fmaf(dr, (float)h[5], bb1.y), 0.f);
                v[6] = (_Float16)fmaxf(fmaf(dr, (float)h[6], bb1.z), 0.f);
                v[7] = (_Float16)fmaxf(fmaf(dr, (float)h[7], bb1.w), 0.f);
                a[kt] = v;
            } else {
                const float4 v0 = *(const float4*)&inF[row * DIM + k0];
                const float4 v1 = *(const float4*)&inF[row * DIM + k0 + 4];
                f16x8 v;
                v[0] = (_Float16)v0.x; v[1] = (_Float16)v0.y;
                v[2] = (_Float16)v0.z; v[3] = (_Float16)v0.w;
                v[4] = (_Float16)v1.x; v[5] = (_Float16)v1.y;
                v[6] = (_Float16)v1.z; v[7] = (_Float16)v1.w;
                a[kt] = v;
            }
        }
#pragma unroll
        for (int ct = 0; ct < 2; ++ct)
#pragma unroll
            for (int kt = 0; kt < 4; ++kt)
                acc[rt][ct] = __builtin_amdgcn_mfma_f32_16x16x32_f16(a[kt], bf[ct][kt],
                                                                    acc[rt][ct], 0, 0, 0);
    }

    // ---- epilogue: dinv scale, fp16 store ----
#pragma unroll
    for (int rt = 0; rt < 4; ++rt) {
#pragma unroll
        for (int r = 0; r < 4; ++r) {
            const int row = row0 + rt * 16 + ((l >> 4) << 2) + r;
            if (row < NN) {
                const float d = dinv[row];
                outH[row * DIM + colw + l15]      = (_Float16)(acc[rt][0][r] * d);
                outH[row * DIM + colw + 16 + l15] = (_Float16)(acc[rt][1][r] * d);
            }
        }
    }
}

// ---------------- gather (fp16 rows): acc[n] = hs[n] + sum_{j in row n} hs[csr[j]] ----------------
template <int FINAL>
__global__ void k_gather(const __half* __restrict__ hs, __half* __restrict__ outH,
                         float* __restrict__ outF, const int* __restrict__ csr,
                         const int* __restrict__ rowptr, const float* __restrict__ dinv,
                         const float* __restrict__ b2) {
    const int w = (blockIdx.x * blockDim.x + threadIdx.x) >> 6;
    if (w >= NN) return;
    const int lane = threadIdx.x & 63;
    const int off  = lane << 1;    // half index

    const int start = __builtin_amdgcn_readfirstlane(rowptr[w]);
    const int end   = __builtin_amdgcn_readfirstlane(rowptr[w + 1]);

    float2 a0 = __half22float2(*(const __half2*)&hs[w * DIM + off]);  // self-loop
    float2 a1 = {0.f, 0.f}, a2 = {0.f, 0.f}, a3 = {0.f, 0.f};

    int j = start;
    for (; j + 3 < end; j += 4) {
        const int s0 = __builtin_amdgcn_readfirstlane(csr[j]);
        const int s1 = __builtin_amdgcn_readfirstlane(csr[j + 1]);
        const int s2 = __builtin_amdgcn_readfirstlane(csr[j + 2]);
        const int s3 = __builtin_amdgcn_readfirstlane(csr[j + 3]);
        const float2 v0 = __half22float2(*(const __half2*)&hs[s0 * DIM + off]);
        const float2 v1 = __half22float2(*(const __half2*)&hs[s1 * DIM + off]);
        const float2 v2 = __half22float2(*(const __half2*)&hs[s2 * DIM + off]);
        const float2 v3 = __half22float2(*(const __half2*)&hs[s3 * DIM + off]);
        a0.x += v0.x; a0.y += v0.y;
        a1.x += v1.x; a1.y += v1.y;
        a2.x += v2.x; a2.y += v2.y;
        a3.x += v3.x; a3.y += v3.y;
    }
    for (; j < end; ++j) {
        const int s0 = __builtin_amdgcn_readfirstlane(csr[j]);
        const float2 v0 = __half22float2(*(const __half2*)&hs[s0 * DIM + off]);
        a0.x += v0.x; a0.y += v0.y;
    }

    float2 r = {a0.x + a1.x + a2.x + a3.x, a0.y + a1.y + a2.y + a3.y};
    if constexpr (FINAL) {
        const float d = dinv[w];
        const float2 b = *(const float2*)&b2[off];
        r.x = fmaf(d, r.x, b.x);
        r.y = fmaf(d, r.y, b.y);
        *(float2*)&outF[w * DIM + off] = r;
    } else {
        *(__half2*)&outH[w * DIM + off] = __floats2half2_rn(r.x, r.y);
    }
}

extern "C" void kernel_launch(void* const* d_in, const int* in_sizes, int n_in,
                              void* d_out, int out_size, void* d_ws, size_t ws_size,
                              hipStream_t stream) {
    const float* x  = (const float*)d_in[0];
    const int*   ei = (const int*)d_in[1];
    const float* W1 = (const float*)d_in[2];
    const float* b1 = (const float*)d_in[3];
    const float* W2 = (const float*)d_in[4];
    const float* b2 = (const float*)d_in[5];
    float* out = (float*)d_out;

    const int E = in_sizes[1] / 2;
    const int* src = ei;        // edge_index[0]
    const int* dst = ei + E;    // edge_index[1]

    char* ws = (char*)d_ws;
    float*    dinv   = (float*)(ws);                        // NN floats
    int*      degi   = (int*)  (ws + (1  << 20));           // NN ints
    int*      rowptr = (int*)  (ws + (2  << 20));           // NN+1 ints
    int*      bsum   = (int*)  (ws + (3  << 20));           // SCAN_NB ints
    int*      bcur   = (int*)  (ws + (3  << 20) + 65536);   // NB ints
    int*      csr    = (int*)  (ws + (4  << 20));           // E ints (6.4 MB)
    int*      binbuf = (int*)  (ws + (11 << 20));           // NB*BCAP ints (8.0 MB)
    _Float16* hs     = (_Float16*)(ws + (20 << 20));        // NN*DIM halfs (25.6 MB)
    _Float16* agg1   = (_Float16*)(ws + (47 << 20));        // NN*DIM halfs (25.6 MB)

    const int ABLK = (E + 4095) / 4096;                     // 391

    // ---- CSR build (all atomics in LDS; global writes cache-clustered) ----
    k_zero    <<<(NB + 255) / 256, 256, 0, stream>>>(bcur, NB);
    k_binA    <<<ABLK, 256, 0, stream>>>(src, dst, bcur, binbuf, E);
    k_binCount<<<NB, 256, 0, stream>>>(bcur, binbuf, degi);
    k_scan1   <<<SCAN_NB, 256, 0, stream>>>(degi, bsum, NN);
    k_scan2   <<<1, 1024, 0, stream>>>(bsum, SCAN_NB);
    k_scan3d  <<<SCAN_NB, 256, 0, stream>>>(degi, bsum, rowptr, dinv, NN);

    // ---- layer 1: fill CSR (391 blocks) + MFMA GEMM1 (1563 tiles) fused ----
    k_gemm<0, 1><<<NB + GTILES, 256, 0, stream>>>(x, nullptr, W1, dinv, nullptr, hs,
                                                  rowptr, bcur, binbuf, csr);
    k_gather<0> <<<(NN * 64) / 256, 256, 0, stream>>>((const __half*)hs, (__half*)agg1,
                                                      nullptr, csr, rowptr, dinv, nullptr);

    // ---- layer 2 ----
    k_gemm<1, 0><<<GTILES, 256, 0, stream>>>(nullptr, agg1, W2, dinv, b1, hs,
                                             rowptr, bcur, binbuf, csr);
    k_gather<1> <<<(NN * 64) / 256, 256, 0, stream>>>((const __half*)hs, nullptr, out,
                                                      csr, rowptr, dinv, b2);
}